// Round 18
// baseline (489.985 us; speedup 1.0000x reference)
//
#include <hip/hip_runtime.h>

#define E_EDGES 320000
#define NSENT   100000
#define NSENT_P 100096
#define NSECT   20000
#define NSECT_P 20096
#define SDIM    256
#define TDIM    512
#define FFN     2048
#define SENT_CONV_BLOCKS (NSENT_P * SDIM / 8 / 256)   // 12512
#define SECT_CONV_BLOCKS (NSECT_P / 4)                // 5024
#define CONV_BLOCKS (SENT_CONV_BLOCKS + SECT_CONV_BLOCKS)  // 17536
#define HIST_BLOCKS (2 * E_EDGES / 256)               // 2500
#define SCAT_BLOCKS 2504                              // pad to %8==0
#define FS1_BLOCKS ((NSENT_P / 128) * 4)              // 3128 (%8==0)
#define F2_BLOCKS  ((NSECT_P / 64) * 4)               // 1256 (%8==0)

typedef short bf16x8 __attribute__((ext_vector_type(8)));
typedef float f32x4  __attribute__((ext_vector_type(4)));

static __device__ __forceinline__ float bf2f(unsigned short u) {
    unsigned int i = ((unsigned int)u) << 16;
    float f; __builtin_memcpy(&f, &i, 4); return f;
}
static __device__ __forceinline__ unsigned short f2bf(float f) {
    unsigned int i; __builtin_memcpy(&i, &f, 4);
    unsigned int r = i + 0x7FFFu + ((i >> 16) & 1u);
    return (unsigned short)(r >> 16);
}

// async global->LDS, 16B per lane, dest = wave-uniform base + lane*16
static __device__ __forceinline__ void gload16(const unsigned short* g, unsigned short* l) {
    __builtin_amdgcn_global_load_lds(
        (const __attribute__((address_space(1))) unsigned int*)g,
        (__attribute__((address_space(3))) unsigned int*)l, 16, 0, 0);
}

// ---------------- prep: fold + 4 transposes + cnt zeroing (one launch) ---
__global__ __launch_bounds__(256)
void k_prep(const float* __restrict__ W1d, const float* __restrict__ ar1, float* __restrict__ Wr1,
            const float* __restrict__ W1s, unsigned short* __restrict__ w1t,
            const float* __restrict__ W2,  unsigned short* __restrict__ w2t,
            const float* __restrict__ fw1, unsigned short* __restrict__ fw1t,
            const float* __restrict__ fw2, unsigned short* __restrict__ fw2t,
            int* __restrict__ cnt1, int* __restrict__ cnt2)
{
    int b = blockIdx.x, tid = threadIdx.x;
    if (b < 16) {                        // fold: Wr1[k,h] = sum_d W1d[k,h*64+d]*ar1[h,d]
        int t = b * 256 + tid;
        int k = t >> 3, h = t & 7;
        float s = 0.f;
        for (int d = 0; d < 64; ++d) s += W1d[k * 512 + h * 64 + d] * ar1[h * 64 + d];
        Wr1[t] = s;
        return;
    }
    if (b >= 2448) {                     // zero cnt arrays
        int zb = b - 2448;
        int idx = (zb < 79 ? zb : zb - 79) * 256 + tid;
        if (idx < NSECT) { if (zb < 79) cnt1[idx] = 0; else cnt2[idx] = 0; }
        return;
    }
    const float* in; unsigned short* out; int R, C, gx, local;
    if      (b < 144)  { local = b - 16;   in = W1s; out = w1t;  R = 256;  C = 512;  gx = 16; }
    else if (b < 400)  { local = b - 144;  in = W2;  out = w2t;  R = 512;  C = 512;  gx = 16; }
    else if (b < 1424) { local = b - 400;  in = fw1; out = fw1t; R = 512;  C = 2048; gx = 64; }
    else               { local = b - 1424; in = fw2; out = fw2t; R = 2048; C = 512;  gx = 16; }
    int bx = local % gx, by = local / gx;
    __shared__ float tile[32][33];
    int c0 = bx * 32, r0 = by * 32;
    int tx = tid & 31, ty = tid >> 5;
#pragma unroll
    for (int i = 0; i < 4; ++i)
        tile[ty + i * 8][tx] = in[(long)(r0 + ty + i * 8) * C + c0 + tx];
    __syncthreads();
#pragma unroll
    for (int i = 0; i < 4; ++i)
        out[(long)(c0 + ty + i * 8) * R + r0 + tx] = f2bf(tile[tx][ty + i * 8]);
}

// ---- converts + er1 proj (Wr1 from k_prep) + hist tail (one launch) ----
__global__ __launch_bounds__(256)
void k_convert_all(const float* __restrict__ sent, unsigned short* __restrict__ sent_b,
                   const float* __restrict__ sect, unsigned short* __restrict__ sect_b,
                   const float* __restrict__ Wf, float* __restrict__ er1,
                   const int* __restrict__ dst1, int* __restrict__ cnt1,
                   const int* __restrict__ dst2, int* __restrict__ cnt2)
{
    int b = blockIdx.x, tid = threadIdx.x;
    if (b >= CONV_BLOCKS) {              // ---- hist ----
        int i = (b - CONV_BLOCKS) * 256 + tid;
        if (i < E_EDGES) atomicAdd(&cnt1[dst1[i]], 1);
        else             atomicAdd(&cnt2[dst2[i - E_EDGES]], 1);
        return;
    }
    if (b < SENT_CONV_BLOCKS) {          // ---- sent convert ----
        long i8 = (((long)b * 256) + tid) * 8;
        int row = (int)(i8 >> 8);        // SDIM = 256
        uint4 o;
        if (row < NSENT) {
            float4 v0 = *(const float4*)(sent + i8);
            float4 v1 = *(const float4*)(sent + i8 + 4);
            o.x = ((unsigned int)f2bf(v0.x)) | (((unsigned int)f2bf(v0.y)) << 16);
            o.y = ((unsigned int)f2bf(v0.z)) | (((unsigned int)f2bf(v0.w)) << 16);
            o.z = ((unsigned int)f2bf(v1.x)) | (((unsigned int)f2bf(v1.y)) << 16);
            o.w = ((unsigned int)f2bf(v1.z)) | (((unsigned int)f2bf(v1.w)) << 16);
        } else { o = make_uint4(0u, 0u, 0u, 0u); }
        *(uint4*)(sent_b + i8) = o;
        return;
    }
    // ---- sect convert + er1 projection (register weights from Wf) ----
    int lane = tid & 63;
    int row  = (b - SENT_CONV_BLOCKS) * 4 + (tid >> 6);
    f32x4 w[16];
    const f32x4* wp = (const f32x4*)(Wf + lane * 64);
#pragma unroll
    for (int i = 0; i < 16; ++i) w[i] = wp[i];
    if (row >= NSECT_P) return;
    if (row >= NSECT) {
        *(uint4*)(sect_b + (long)row * TDIM + lane * 8) = make_uint4(0u, 0u, 0u, 0u);
        return;
    }
    float4 x0 = *(const float4*)(sect + (long)row * TDIM + lane * 8);
    float4 x1 = *(const float4*)(sect + (long)row * TDIM + lane * 8 + 4);
    uint4 o;
    o.x = ((unsigned int)f2bf(x0.x)) | (((unsigned int)f2bf(x0.y)) << 16);
    o.y = ((unsigned int)f2bf(x0.z)) | (((unsigned int)f2bf(x0.w)) << 16);
    o.z = ((unsigned int)f2bf(x1.x)) | (((unsigned int)f2bf(x1.y)) << 16);
    o.w = ((unsigned int)f2bf(x1.z)) | (((unsigned int)f2bf(x1.w)) << 16);
    *(uint4*)(sect_b + (long)row * TDIM + lane * 8) = o;

    float xs[8] = {x0.x, x0.y, x0.z, x0.w, x1.x, x1.y, x1.z, x1.w};
    float p[8] = {};
#pragma unroll
    for (int j = 0; j < 8; ++j) {
        f32x4 wa = w[j * 2], wb = w[j * 2 + 1];
        p[0] += xs[j] * wa[0]; p[1] += xs[j] * wa[1];
        p[2] += xs[j] * wa[2]; p[3] += xs[j] * wa[3];
        p[4] += xs[j] * wb[0]; p[5] += xs[j] * wb[1];
        p[6] += xs[j] * wb[2]; p[7] += xs[j] * wb[3];
    }
#pragma unroll
    for (int s = 1; s < 64; s <<= 1)
#pragma unroll
        for (int h = 0; h < 8; ++h) p[h] += __shfl_xor(p[h], s);
    if (lane == 0) {
        *(float4*)(er1 + (long)row * 8)     = make_float4(p[0], p[1], p[2], p[3]);
        *(float4*)(er1 + (long)row * 8 + 4) = make_float4(p[4], p[5], p[6], p[7]);
    }
}

// -------- GEMM body (LDS via pointers so kernels can share/merge) -------
// a_sm layout: [KU][MT*32][32] packed; b_sm: [KU][128][32] packed.
template<int EPI, int NATT, int MT, int KU>
static __device__ __forceinline__ void gemm_body(
    unsigned short* a_sm, unsigned short* b_sm, int bid, int gnwg,
    const unsigned short* __restrict__ A, const unsigned short* __restrict__ BT,
    void* __restrict__ C, const float* __restrict__ bias,
    int N, int K, int Mreal, int ntx,
    const float* __restrict__ av0, float* __restrict__ eo0,
    const float* __restrict__ av1, float* __restrict__ eo1)
{
#define A_AT(u, row) (a_sm + ((u) * (MT * 32) + (row)) * 32)
#define B_AT(u, row) (b_sm + ((u) * 128 + (row)) * 32)
    const int tid  = threadIdx.x;
    const int lane = tid & 63;
    const int wid  = tid >> 6;
    const int wr   = (wid >> 1) * (16 * MT);
    const int wc   = (wid & 1) * 64;

    const int q = gnwg >> 3, r = gnwg & 7;
    const int xcd = bid & 7;
    const int wgid = (xcd < r ? xcd * (q + 1) : r * (q + 1) + (xcd - r) * q) + (bid >> 3);
    const int row0 = (wgid / ntx) * (32 * MT);
    const int col0 = (wgid % ntx) * 128;

    const int l4 = lane >> 2;
    const int lc = (lane & 3) * 8;

    const unsigned short* gA0;
    const unsigned short* gA1 = nullptr;
    if (MT == 2) {
        gA0 = A + (long)(row0 + 16 * wid + l4) * K + lc;
    } else {
        gA0 = A + (long)(row0 + 16 * (2 * wid) + l4) * K + lc;
        gA1 = A + (long)(row0 + 16 * (2 * wid + 1) + l4) * K + lc;
    }
    const unsigned short* gB0 = BT + (long)(col0 + 16 * (2 * wid) + l4) * K + lc;
    const unsigned short* gB1 = BT + (long)(col0 + 16 * (2 * wid + 1) + l4) * K + lc;

    f32x4 acc[MT][4] = {};

    for (int k0 = 0; k0 < K; k0 += 32 * KU) {
        __syncthreads();
#pragma unroll
        for (int u = 0; u < KU; ++u) {
            if (MT == 2) {
                gload16(gA0 + k0 + 32 * u, A_AT(u, 16 * wid));
            } else {
                gload16(gA0 + k0 + 32 * u, A_AT(u, 32 * wid));
                gload16(gA1 + k0 + 32 * u, A_AT(u, 32 * wid + 16));
            }
            gload16(gB0 + k0 + 32 * u, B_AT(u, 32 * wid));
            gload16(gB1 + k0 + 32 * u, B_AT(u, 32 * wid + 16));
        }
        __syncthreads();
#pragma unroll
        for (int u = 0; u < KU; ++u) {
            bf16x8 af[MT], bfr[4];
#pragma unroll
            for (int m = 0; m < MT; ++m)
                af[m] = *(const bf16x8*)(A_AT(u, wr + m * 16 + (lane & 15)) + 8 * (lane >> 4));
#pragma unroll
            for (int n = 0; n < 4; ++n)
                bfr[n] = *(const bf16x8*)(B_AT(u, wc + n * 16 + (lane & 15)) + 8 * (lane >> 4));
#pragma unroll
            for (int m = 0; m < MT; ++m)
#pragma unroll
                for (int n = 0; n < 4; ++n)
                    acc[m][n] = __builtin_amdgcn_mfma_f32_16x16x32_bf16(af[m], bfr[n], acc[m][n], 0, 0, 0);
        }
    }

#pragma unroll
    for (int m = 0; m < MT; ++m) {
        int row_t = wr + m * 16 + ((lane >> 4) << 2);
#pragma unroll
        for (int n = 0; n < 4; ++n) {
            int col = col0 + wc + n * 16 + (lane & 15);
#pragma unroll
            for (int r2 = 0; r2 < 4; ++r2) {
                int row = row0 + row_t + r2;
                float v = acc[m][n][r2];
                if (EPI >= 1) v += bias[col];
                if (EPI == 1) v = fmaxf(v, 0.f);
                if (EPI <= 1) {
                    ((unsigned short*)C)[(long)row * N + col] = f2bf(v);
                } else {
                    if (row < Mreal) ((float*)C)[(long)row * N + col] = v;
                }
            }
        }
    }

    if (NATT >= 1) {
        int hw = (col0 + wc) >> 6;
        float av0r[4], av1r[4];
#pragma unroll
        for (int n = 0; n < 4; ++n) {
            int c = col0 + wc + n * 16 + (lane & 15);
            av0r[n] = av0[c];
            if (NATT == 2) av1r[n] = av1[c];
        }
        float red0[MT * 4], red1[MT * 4];
#pragma unroll
        for (int m = 0; m < MT; ++m)
#pragma unroll
            for (int r2 = 0; r2 < 4; ++r2) {
                red0[m * 4 + r2] = acc[m][0][r2] * av0r[0] + acc[m][1][r2] * av0r[1]
                                 + acc[m][2][r2] * av0r[2] + acc[m][3][r2] * av0r[3];
                if (NATT == 2)
                    red1[m * 4 + r2] = acc[m][0][r2] * av1r[0] + acc[m][1][r2] * av1r[1]
                                     + acc[m][2][r2] * av1r[2] + acc[m][3][r2] * av1r[3];
            }
#pragma unroll
        for (int s = 1; s < 16; s <<= 1)
#pragma unroll
            for (int j = 0; j < MT * 4; ++j) {
                red0[j] += __shfl_xor(red0[j], s);
                if (NATT == 2) red1[j] += __shfl_xor(red1[j], s);
            }
        if ((lane & 15) == 0) {
#pragma unroll
            for (int m = 0; m < MT; ++m)
#pragma unroll
                for (int r2 = 0; r2 < 4; ++r2) {
                    int row = row0 + wr + m * 16 + ((lane >> 4) << 2) + r2;
                    eo0[row * 8 + hw] = red0[m * 4 + r2];
                    if (NATT == 2) eo1[row * 8 + hw] = red1[m * 4 + r2];
                }
        }
    }
#undef A_AT
#undef B_AT
}

// ---------------- standalone GEMM (FFN1 / FFN2) -------------------------
template<int EPI, int NATT, int MT, int KU>
__global__ __launch_bounds__(256)
void k_gemm(const unsigned short* __restrict__ A, const unsigned short* __restrict__ BT,
            void* __restrict__ C, const float* __restrict__ bias,
            int N, int K, int Mreal, int ntx,
            const float* __restrict__ av0, float* __restrict__ eo0,
            const float* __restrict__ av1, float* __restrict__ eo1)
{
    __shared__ unsigned short a_s[KU * MT * 32 * 32];
    __shared__ unsigned short b_s[KU * 128 * 32];
    gemm_body<EPI, NATT, MT, KU>(a_s, b_s, blockIdx.x, gridDim.x,
                                 A, BT, C, bias, N, K, Mreal, ntx,
                                 av0, eo0, av1, eo1);
}

// ---- merged feature stage: scatter + fs1 GEMM + f2 GEMM (one launch) ---
// blocks [0, SCAT_BLOCKS): CSR scatter (both graphs, overlaps the GEMMs)
// blocks [SCAT_BLOCKS, +FS1_BLOCKS): fs1 GEMM (MT=4, NATT=1)
// blocks [.., +F2_BLOCKS): f2 GEMM (MT=2, NATT=2)
// All sub-range offsets are %8==0 so bid&7 == physical XCD within range.
__global__ __launch_bounds__(256)
void k_feat(const unsigned short* __restrict__ sent_b, const unsigned short* __restrict__ w1t,
            unsigned short* __restrict__ fs1,
            const float* __restrict__ al1, float* __restrict__ el1,
            const unsigned short* __restrict__ sect_b, const unsigned short* __restrict__ w2t,
            unsigned short* __restrict__ f2,
            const float* __restrict__ al2, float* __restrict__ el2,
            const float* __restrict__ ar2, float* __restrict__ er2,
            const int* __restrict__ sc_src1, const int* __restrict__ sc_dst1,
            int* __restrict__ sc_cur1, int* __restrict__ sc_srcs1,
            const int* __restrict__ sc_src2, const int* __restrict__ sc_dst2,
            int* __restrict__ sc_cur2, int* __restrict__ sc_srcs2)
{
    __shared__ unsigned short a_s[2 * 128 * 32];     // max: KU=2, MT=4
    __shared__ unsigned short b_s[2 * 128 * 32];
    int b = blockIdx.x;
    if (b < SCAT_BLOCKS) {               // ---- scatter ----
        int i = b * 256 + threadIdx.x;
        if (i < E_EDGES) {
            int p = atomicAdd(&sc_cur1[sc_dst1[i]], 1);
            sc_srcs1[p] = sc_src1[i];
        } else if (i < 2 * E_EDGES) {
            int j = i - E_EDGES;
            int p = atomicAdd(&sc_cur2[sc_dst2[j]], 1);
            sc_srcs2[p] = sc_src2[j];
        }
        return;
    }
    b -= SCAT_BLOCKS;
    if (b < FS1_BLOCKS) {                // ---- fs1 GEMM ----
        gemm_body<0, 1, 4, 2>(a_s, b_s, b, FS1_BLOCKS,
                              sent_b, w1t, fs1, nullptr, 512, 256, 0, 4,
                              al1, el1, nullptr, nullptr);
        return;
    }
    b -= FS1_BLOCKS;                     // ---- f2 GEMM ----
    gemm_body<0, 2, 2, 2>(a_s, b_s, b, F2_BLOCKS,
                          sect_b, w2t, f2, nullptr, 512, 512, 0, 4,
                          al2, el2, ar2, er2);
}

// ---------------- scan (both graphs, one launch) ------------------------
__global__ void k_scan2(const int* __restrict__ cnt1, int* __restrict__ off1, int* __restrict__ cur1,
                        const int* __restrict__ cnt2, int* __restrict__ off2, int* __restrict__ cur2)
{
    const int* cnt = blockIdx.x ? cnt2 : cnt1;
    int* off = blockIdx.x ? off2 : off1;
    int* cur = blockIdx.x ? cur2 : cur1;
    __shared__ int partial[1024];
    int t = threadIdx.x;
    const int Nseg = NSECT;
    int chunk = (Nseg + 1023) / 1024;
    int b = t * chunk;
    int e_ = b + chunk; if (e_ > Nseg) e_ = Nseg; if (b > Nseg) b = Nseg;
    int s = 0;
    for (int i = b; i < e_; ++i) s += cnt[i];
    partial[t] = s;
    __syncthreads();
    for (int d = 1; d < 1024; d <<= 1) {
        int v = partial[t];
        int w = (t >= d) ? partial[t - d] : 0;
        __syncthreads();
        partial[t] = v + w;
        __syncthreads();
    }
    int run = (t == 0) ? 0 : partial[t - 1];
    for (int i = b; i < e_; ++i) { off[i] = run; cur[i] = run; run += cnt[i]; }
    if (t == 1023) off[Nseg] = partial[1023];
}

// -------- GAT aggregate core: max pass + fused denom/message pass -------
static __device__ __forceinline__ void agg_core(
    const unsigned short* __restrict__ fs, const float* __restrict__ el,
    const float* __restrict__ er, const float* __restrict__ bias,
    const int* __restrict__ off, const int* __restrict__ srcs,
    int n, int lane, float o[8])
{
    int h8 = lane & 7;
    int beg = off[n], end = off[n + 1];
    float er_h = er[n * 8 + h8];

    float mx = -3.0e38f;
    for (int p = beg + (lane >> 3); p < end; p += 8) {
        int s = srcs[p];
        float e = el[s * 8 + h8] + er_h;
        e = (e >= 0.f) ? e : 0.2f * e;
        mx = fmaxf(mx, e);
    }
    mx = fmaxf(mx, __shfl_xor(mx, 8));
    mx = fmaxf(mx, __shfl_xor(mx, 16));
    mx = fmaxf(mx, __shfl_xor(mx, 32));

    int hc = lane >> 3;                 // head owned by this lane's 8 dims
    float mx_c = __shfl(mx, hc);
    float er_c = er[n * 8 + hc];

    float a0=0,a1=0,a2=0,a3=0,a4=0,a5=0,a6=0,a7=0,sw=0;
    const unsigned short* fsl = fs + lane * 8;

#define ACC8(vv, ww)                                                   \
    a0 += (ww) * bf2f((unsigned short)((vv).x & 0xFFFF));              \
    a1 += (ww) * bf2f((unsigned short)((vv).x >> 16));                 \
    a2 += (ww) * bf2f((unsigned short)((vv).y & 0xFFFF));              \
    a3 += (ww) * bf2f((unsigned short)((vv).y >> 16));                 \
    a4 += (ww) * bf2f((unsigned short)((vv).z & 0xFFFF));              \
    a5 += (ww) * bf2f((unsigned short)((vv).z >> 16));                 \
    a6 += (ww) * bf2f((unsigned short)((vv).w & 0xFFFF));              \
    a7 += (ww) * bf2f((unsigned short)((vv).w >> 16));

    int p = beg;
    for (; p + 4 <= end; p += 4) {
        int s0 = srcs[p + 0], s1 = srcs[p + 1], s2 = srcs[p + 2], s3 = srcs[p + 3];
        float g0 = el[s0 * 8 + hc], g1 = el[s1 * 8 + hc];
        float g2 = el[s2 * 8 + hc], g3 = el[s3 * 8 + hc];
        uint4 v0 = *(const uint4*)(fsl + (long)s0 * 512);
        uint4 v1 = *(const uint4*)(fsl + (long)s1 * 512);
        uint4 v2 = *(const uint4*)(fsl + (long)s2 * 512);
        uint4 v3 = *(const uint4*)(fsl + (long)s3 * 512);
        float e0 = g0 + er_c; e0 = (e0 >= 0.f) ? e0 : 0.2f * e0; float w0 = __expf(e0 - mx_c);
        float e1 = g1 + er_c; e1 = (e1 >= 0.f) ? e1 : 0.2f * e1; float w1 = __expf(e1 - mx_c);
        float e2 = g2 + er_c; e2 = (e2 >= 0.f) ? e2 : 0.2f * e2; float w2 = __expf(e2 - mx_c);
        float e3 = g3 + er_c; e3 = (e3 >= 0.f) ? e3 : 0.2f * e3; float w3 = __expf(e3 - mx_c);
        sw += w0 + w1 + w2 + w3;
        ACC8(v0, w0); ACC8(v1, w1); ACC8(v2, w2); ACC8(v3, w3);
    }
    for (; p < end; ++p) {
        int s = srcs[p];
        float e = el[s * 8 + hc] + er_c;
        e = (e >= 0.f) ? e : 0.2f * e;
        float ww0 = __expf(e - mx_c);
        sw += ww0;
        uint4 v = *(const uint4*)(fsl + (long)s * 512);
        ACC8(v, ww0);
    }
#undef ACC8

    float inv = 1.f / fmaxf(sw, 1e-9f);
    const float* bp = bias + lane * 8;
    o[0] = a0*inv + bp[0]; o[1] = a1*inv + bp[1]; o[2] = a2*inv + bp[2]; o[3] = a3*inv + bp[3];
    o[4] = a4*inv + bp[4]; o[5] = a5*inv + bp[5]; o[6] = a6*inv + bp[6]; o[7] = a7*inv + bp[7];
#pragma unroll
    for (int j = 0; j < 8; ++j) o[j] = (o[j] > 0.f) ? o[j] : (__expf(o[j]) - 1.f);
}

// ---- both aggregates + fusion gate + residual, wave-per-(node,graph) ---
__global__ __launch_bounds__(256)
void k_agg_both(const unsigned short* __restrict__ fs1, const float* __restrict__ el1,
                const float* __restrict__ er1, const float* __restrict__ b1,
                const int* __restrict__ off1, const int* __restrict__ srcs1,
                const unsigned short* __restrict__ f2, const float* __restrict__ el2,
                const float* __restrict__ er2, const float* __restrict__ b2,
                const int* __restrict__ off2, const int* __restrict__ srcs2,
                const float* __restrict__ sect, const float* __restrict__ fw,
                const float* __restrict__ fb, unsigned short* __restrict__ hout)
{
    __shared__ float sh_o2[2][512];      // S2S result per local node, 4 KB
    int wid  = threadIdx.x >> 6;
    int lane = threadIdx.x & 63;
    int nloc = wid >> 1;
    int graph = wid & 1;
    int n = blockIdx.x * 2 + nloc;       // grid = NSECT_P/2, always in range
    bool real = (n < NSECT);

    float o1[8];
    if (real) {
        if (graph == 0) {
            agg_core(fs1, el1, er1, b1, off1, srcs1, n, lane, o1);   // s2S
        } else {
            float o2[8];
            agg_core(f2, el2, er2, b2, off2, srcs2, n, lane, o2);    // S2S
            *(float4*)&sh_o2[nloc][lane * 8]     = make_float4(o2[0], o2[1], o2[2], o2[3]);
            *(float4*)&sh_o2[nloc][lane * 8 + 4] = make_float4(o2[4], o2[5], o2[6], o2[7]);
        }
    }
    __syncthreads();
    if (graph != 0) return;
    long base = (long)n * TDIM + lane * 8;
    if (!real) {                          // pad rows of h: zero bf16
        *(uint4*)(hout + base) = make_uint4(0u, 0u, 0u, 0u);
        return;
    }
    float4 q0 = *(const float4*)&sh_o2[nloc][lane * 8];
    float4 q1 = *(const float4*)&sh_o2[nloc][lane * 8 + 4];
    float o2[8] = {q0.x, q0.y, q0.z, q0.w, q1.x, q1.y, q1.z, q1.w};

    float4 wa0 = *(const float4*)(fw + lane * 8);
    float4 wa1 = *(const float4*)(fw + lane * 8 + 4);
    float4 wb0 = *(const float4*)(fw + 512 + lane * 8);
    float4 wb1 = *(const float4*)(fw + 512 + lane * 8 + 4);
    float part = o1[0]*wa0.x + o1[1]*wa0.y + o1[2]*wa0.z + o1[3]*wa0.w
               + o1[4]*wa1.x + o1[5]*wa1.y + o1[6]*wa1.z + o1[7]*wa1.w
               + o2[0]*wb0.x + o2[1]*wb0.y + o2[2]*wb0.z + o2[3]*wb0.w
               + o2[4]*wb1.x + o2[5]*wb1.y + o2[6]*wb1.z + o2[7]*wb1.w;
#pragma unroll
    for (int s = 1; s < 64; s <<= 1) part += __shfl_xor(part, s);
    float z = 1.f / (1.f + __expf(-(part + fb[0])));
    float4 r0 = *(const float4*)(sect + base);
    float4 r1 = *(const float4*)(sect + base + 4);
    float hv[8];
    hv[0] = r0.x + z * o1[0] + (1.f - z) * o2[0];
    hv[1] = r0.y + z * o1[1] + (1.f - z) * o2[1];
    hv[2] = r0.z + z * o1[2] + (1.f - z) * o2[2];
    hv[3] = r0.w + z * o1[3] + (1.f - z) * o2[3];
    hv[4] = r1.x + z * o1[4] + (1.f - z) * o2[4];
    hv[5] = r1.y + z * o1[5] + (1.f - z) * o2[5];
    hv[6] = r1.z + z * o1[6] + (1.f - z) * o2[6];
    hv[7] = r1.w + z * o1[7] + (1.f - z) * o2[7];
    uint4 u;
    u.x = ((unsigned int)f2bf(hv[0])) | (((unsigned int)f2bf(hv[1])) << 16);
    u.y = ((unsigned int)f2bf(hv[2])) | (((unsigned int)f2bf(hv[3])) << 16);
    u.z = ((unsigned int)f2bf(hv[4])) | (((unsigned int)f2bf(hv[5])) << 16);
    u.w = ((unsigned int)f2bf(hv[6])) | (((unsigned int)f2bf(hv[7])) << 16);
    *(uint4*)(hout + base) = u;
}

// ------------------------------------------------------------------------
extern "C" void kernel_launch(void* const* d_in, const int* in_sizes, int n_in,
                              void* d_out, int out_size, void* d_ws, size_t ws_size,
                              hipStream_t stream)
{
    (void)in_sizes; (void)n_in; (void)out_size; (void)ws_size;
    const float* sent    = (const float*)d_in[0];
    const float* sect    = (const float*)d_in[1];
    const int*   s2S_src = (const int*)d_in[2];
    const int*   s2S_dst = (const int*)d_in[3];
    const int*   S2S_src = (const int*)d_in[4];
    const int*   S2S_dst = (const int*)d_in[5];
    const float* W1_src  = (const float*)d_in[6];
    const float* W1_dst  = (const float*)d_in[7];
    const float* al1     = (const float*)d_in[8];
    const float* ar1     = (const float*)d_in[9];
    const float* b1      = (const float*)d_in[10];
    const float* W2      = (const float*)d_in[11];
    const float* al2     = (const float*)d_in[12];
    const float* ar2     = (const float*)d_in[13];
    const float* b2      = (const float*)d_in[14];
    const float* fus_w   = (const float*)d_in[15];
    const float* fus_b   = (const float*)d_in[16];
    const float* ffn_w1  = (const float*)d_in[17];
    const float* ffn_b1  = (const float*)d_in[18];
    const float* ffn_w2  = (const float*)d_in[19];
    const float* ffn_b2  = (const float*)d_in[20];

    char* ws = (char*)d_ws;
    size_t curo = 0;
    auto alloc = [&](size_t sz) -> void* {
        void* p = ws + curo; curo += (sz + 255) & ~(size_t)255; return p;
    };

    unsigned short* sent_b = (unsigned short*)alloc((size_t)NSENT_P * SDIM * 2);
    unsigned short* sect_b = (unsigned short*)alloc((size_t)NSECT_P * TDIM * 2);
    unsigned short* w1t    = (unsigned short*)alloc((size_t)512 * 256 * 2);
    unsigned short* w2t    = (unsigned short*)alloc((size_t)512 * 512 * 2);
    unsigned short* fw1t   = (unsigned short*)alloc((size_t)2048 * 512 * 2);
    unsigned short* fw2t   = (unsigned short*)alloc((size_t)512 * 2048 * 2);
    float* Wr1 = (float*)alloc(512 * 8 * 4);
    float* el1 = (float*)alloc((size_t)NSENT_P * 8 * 4);
    float* er1 = (float*)alloc((size_t)NSECT_P * 8 * 4);
    float* el2 = (float*)alloc((size_t)NSECT_P * 8 * 4);
    float* er2 = (float*)alloc((size_t)NSECT_P * 8 * 4);
    unsigned short* fs1 = (unsigned short*)alloc((size_t)NSENT_P * 512 * 2);
    unsigned short* f2  = (unsigned short*)alloc((size_t)NSECT_P * 512 * 2);
    int* cnt1 = (int*)alloc((size_t)NSECT * 4);
    int* cnt2 = (int*)alloc((size_t)NSECT * 4);
    int* off1 = (int*)alloc((size_t)(NSECT + 1) * 4);
    int* off2 = (int*)alloc((size_t)(NSECT + 1) * 4);
    int* cur1 = (int*)alloc((size_t)NSECT * 4);
    int* cur2 = (int*)alloc((size_t)NSECT * 4);
    int* srcs1 = (int*)alloc((size_t)E_EDGES * 4);
    int* srcs2 = (int*)alloc((size_t)E_EDGES * 4);
    unsigned short* hb = (unsigned short*)alloc((size_t)NSECT_P * TDIM * 2);
    unsigned short* tb = fs1;   // alias: t[20096,2048] bf16 over fs1, fs1 dead by then

    // 1. prep: fold + transposes + cnt zeroing (one launch)
    k_prep<<<2606, 256, 0, stream>>>(W1_dst, ar1, Wr1, W1_src, w1t, W2, w2t,
                                     ffn_w1, fw1t, ffn_w2, fw2t, cnt1, cnt2);

    // 2. converts + er1 (Wr1 from step 1) + hist tail (one launch)
    k_convert_all<<<CONV_BLOCKS + HIST_BLOCKS, 256, 0, stream>>>(
        sent, sent_b, sect, sect_b, Wr1, er1, s2S_dst, cnt1, S2S_dst, cnt2);

    // 3. prefix scan (both graphs)
    k_scan2<<<2, 1024, 0, stream>>>(cnt1, off1, cur1, cnt2, off2, cur2);

    // 4. merged feature stage: scatter + fs1 GEMM + f2 GEMM (one launch)
    k_feat<<<SCAT_BLOCKS + FS1_BLOCKS + F2_BLOCKS, 256, 0, stream>>>(
        sent_b, w1t, fs1, al1, el1,
        sect_b, w2t, f2, al2, el2, ar2, er2,
        s2S_src, s2S_dst, cur1, srcs1, S2S_src, S2S_dst, cur2, srcs2);

    // 5. both aggregations + fusion gate + residual -> hb (one launch)
    k_agg_both<<<NSECT_P / 2, 256, 0, stream>>>(fs1, el1, er1, b1, off1, srcs1,
                                                f2, el2, er2, b2, off2, srcs2,
                                                sect, fus_w, fus_b, hb);

    // 6. FFN (KU=2 on both)
    k_gemm<1, 0, 4, 2><<<(NSECT_P / 128) * (FFN / 128), 256, 0, stream>>>(
        hb, fw1t, tb, ffn_b1, FFN, 512, 0, FFN / 128,
        nullptr, nullptr, nullptr, nullptr);
    k_gemm<2, 0, 2, 2><<<(NSECT_P / 64) * 4, 256, 0, stream>>>(
        tb, fw2t, d_out, ffn_b2, 512, FFN, NSECT, 4,
        nullptr, nullptr, nullptr, nullptr);
}

// Round 19
// 474.574 us; speedup vs baseline: 1.0325x; 1.0325x over previous
//
#include <hip/hip_runtime.h>

#define E_EDGES 320000
#define NSENT   100000
#define NSENT_P 100096
#define NSECT   20000
#define NSECT_P 20096
#define SDIM    256
#define TDIM    512
#define FFN     2048
#define SENT_CONV_BLOCKS (NSENT_P * SDIM / 8 / 256)   // 12512
#define SECT_CONV_BLOCKS (NSECT_P / 4)                // 5024
#define CONV_BLOCKS (SENT_CONV_BLOCKS + SECT_CONV_BLOCKS)  // 17536
#define HIST_BLOCKS (2 * E_EDGES / 256)               // 2500

typedef short bf16x8 __attribute__((ext_vector_type(8)));
typedef float f32x4  __attribute__((ext_vector_type(4)));

static __device__ __forceinline__ float bf2f(unsigned short u) {
    unsigned int i = ((unsigned int)u) << 16;
    float f; __builtin_memcpy(&f, &i, 4); return f;
}
static __device__ __forceinline__ unsigned short f2bf(float f) {
    unsigned int i; __builtin_memcpy(&i, &f, 4);
    unsigned int r = i + 0x7FFFu + ((i >> 16) & 1u);
    return (unsigned short)(r >> 16);
}

// async global->LDS, 16B per lane, dest = wave-uniform base + lane*16
static __device__ __forceinline__ void gload16(const unsigned short* g, unsigned short* l) {
    __builtin_amdgcn_global_load_lds(
        (const __attribute__((address_space(1))) unsigned int*)g,
        (__attribute__((address_space(3))) unsigned int*)l, 16, 0, 0);
}

// ---------------- prep: fold + 4 transposes + cnt zeroing (one launch) ---
__global__ __launch_bounds__(256)
void k_prep(const float* __restrict__ W1d, const float* __restrict__ ar1, float* __restrict__ Wr1,
            const float* __restrict__ W1s, unsigned short* __restrict__ w1t,
            const float* __restrict__ W2,  unsigned short* __restrict__ w2t,
            const float* __restrict__ fw1, unsigned short* __restrict__ fw1t,
            const float* __restrict__ fw2, unsigned short* __restrict__ fw2t,
            int* __restrict__ cnt1, int* __restrict__ cnt2)
{
    int b = blockIdx.x, tid = threadIdx.x;
    if (b < 16) {                        // fold: Wr1[k,h] = sum_d W1d[k,h*64+d]*ar1[h,d]
        int t = b * 256 + tid;
        int k = t >> 3, h = t & 7;
        float s = 0.f;
        for (int d = 0; d < 64; ++d) s += W1d[k * 512 + h * 64 + d] * ar1[h * 64 + d];
        Wr1[t] = s;
        return;
    }
    if (b >= 2448) {                     // zero cnt arrays
        int zb = b - 2448;
        int idx = (zb < 79 ? zb : zb - 79) * 256 + tid;
        if (idx < NSECT) { if (zb < 79) cnt1[idx] = 0; else cnt2[idx] = 0; }
        return;
    }
    const float* in; unsigned short* out; int R, C, gx, local;
    if      (b < 144)  { local = b - 16;   in = W1s; out = w1t;  R = 256;  C = 512;  gx = 16; }
    else if (b < 400)  { local = b - 144;  in = W2;  out = w2t;  R = 512;  C = 512;  gx = 16; }
    else if (b < 1424) { local = b - 400;  in = fw1; out = fw1t; R = 512;  C = 2048; gx = 64; }
    else               { local = b - 1424; in = fw2; out = fw2t; R = 2048; C = 512;  gx = 16; }
    int bx = local % gx, by = local / gx;
    __shared__ float tile[32][33];
    int c0 = bx * 32, r0 = by * 32;
    int tx = tid & 31, ty = tid >> 5;
#pragma unroll
    for (int i = 0; i < 4; ++i)
        tile[ty + i * 8][tx] = in[(long)(r0 + ty + i * 8) * C + c0 + tx];
    __syncthreads();
#pragma unroll
    for (int i = 0; i < 4; ++i)
        out[(long)(c0 + ty + i * 8) * R + r0 + tx] = f2bf(tile[tx][ty + i * 8]);
}

// ---- converts + er1 proj (Wr1 from k_prep) + hist tail (one launch) ----
__global__ __launch_bounds__(256)
void k_convert_all(const float* __restrict__ sent, unsigned short* __restrict__ sent_b,
                   const float* __restrict__ sect, unsigned short* __restrict__ sect_b,
                   const float* __restrict__ Wf, float* __restrict__ er1,
                   const int* __restrict__ dst1, int* __restrict__ cnt1,
                   const int* __restrict__ dst2, int* __restrict__ cnt2)
{
    int b = blockIdx.x, tid = threadIdx.x;
    if (b >= CONV_BLOCKS) {              // ---- hist ----
        int i = (b - CONV_BLOCKS) * 256 + tid;
        if (i < E_EDGES) atomicAdd(&cnt1[dst1[i]], 1);
        else             atomicAdd(&cnt2[dst2[i - E_EDGES]], 1);
        return;
    }
    if (b < SENT_CONV_BLOCKS) {          // ---- sent convert ----
        long i8 = (((long)b * 256) + tid) * 8;
        int row = (int)(i8 >> 8);        // SDIM = 256
        uint4 o;
        if (row < NSENT) {
            float4 v0 = *(const float4*)(sent + i8);
            float4 v1 = *(const float4*)(sent + i8 + 4);
            o.x = ((unsigned int)f2bf(v0.x)) | (((unsigned int)f2bf(v0.y)) << 16);
            o.y = ((unsigned int)f2bf(v0.z)) | (((unsigned int)f2bf(v0.w)) << 16);
            o.z = ((unsigned int)f2bf(v1.x)) | (((unsigned int)f2bf(v1.y)) << 16);
            o.w = ((unsigned int)f2bf(v1.z)) | (((unsigned int)f2bf(v1.w)) << 16);
        } else { o = make_uint4(0u, 0u, 0u, 0u); }
        *(uint4*)(sent_b + i8) = o;
        return;
    }
    // ---- sect convert + er1 projection (register weights from Wf) ----
    int lane = tid & 63;
    int row  = (b - SENT_CONV_BLOCKS) * 4 + (tid >> 6);
    f32x4 w[16];
    const f32x4* wp = (const f32x4*)(Wf + lane * 64);
#pragma unroll
    for (int i = 0; i < 16; ++i) w[i] = wp[i];
    if (row >= NSECT_P) return;
    if (row >= NSECT) {
        *(uint4*)(sect_b + (long)row * TDIM + lane * 8) = make_uint4(0u, 0u, 0u, 0u);
        return;
    }
    float4 x0 = *(const float4*)(sect + (long)row * TDIM + lane * 8);
    float4 x1 = *(const float4*)(sect + (long)row * TDIM + lane * 8 + 4);
    uint4 o;
    o.x = ((unsigned int)f2bf(x0.x)) | (((unsigned int)f2bf(x0.y)) << 16);
    o.y = ((unsigned int)f2bf(x0.z)) | (((unsigned int)f2bf(x0.w)) << 16);
    o.z = ((unsigned int)f2bf(x1.x)) | (((unsigned int)f2bf(x1.y)) << 16);
    o.w = ((unsigned int)f2bf(x1.z)) | (((unsigned int)f2bf(x1.w)) << 16);
    *(uint4*)(sect_b + (long)row * TDIM + lane * 8) = o;

    float xs[8] = {x0.x, x0.y, x0.z, x0.w, x1.x, x1.y, x1.z, x1.w};
    float p[8] = {};
#pragma unroll
    for (int j = 0; j < 8; ++j) {
        f32x4 wa = w[j * 2], wb = w[j * 2 + 1];
        p[0] += xs[j] * wa[0]; p[1] += xs[j] * wa[1];
        p[2] += xs[j] * wa[2]; p[3] += xs[j] * wa[3];
        p[4] += xs[j] * wb[0]; p[5] += xs[j] * wb[1];
        p[6] += xs[j] * wb[2]; p[7] += xs[j] * wb[3];
    }
#pragma unroll
    for (int s = 1; s < 64; s <<= 1)
#pragma unroll
        for (int h = 0; h < 8; ++h) p[h] += __shfl_xor(p[h], s);
    if (lane == 0) {
        *(float4*)(er1 + (long)row * 8)     = make_float4(p[0], p[1], p[2], p[3]);
        *(float4*)(er1 + (long)row * 8 + 4) = make_float4(p[4], p[5], p[6], p[7]);
    }
}

// ---------------- MFMA GEMM: C[M,N] = A[M,K]bf16 @ BT[N,K]bf16 ----------
// SCAT=1: blocks [gnwg, gridDim.x) perform the CSR scatter for both graphs.
template<int EPI, int NATT, int MT, int KU, int SCAT>
__global__ __launch_bounds__(256)
void k_gemm(const unsigned short* __restrict__ A, const unsigned short* __restrict__ BT,
            void* __restrict__ C, const float* __restrict__ bias,
            int N, int K, int Mreal, int ntx, int gnwg,
            const float* __restrict__ av0, float* __restrict__ eo0,
            const float* __restrict__ av1, float* __restrict__ eo1,
            const int* __restrict__ sc_src1, const int* __restrict__ sc_dst1,
            int* __restrict__ sc_cur1, int* __restrict__ sc_srcs1,
            const int* __restrict__ sc_src2, const int* __restrict__ sc_dst2,
            int* __restrict__ sc_cur2, int* __restrict__ sc_srcs2)
{
    __shared__ unsigned short a_s[KU][MT * 32][32];
    __shared__ unsigned short b_s[KU][128][32];
    const int bid = blockIdx.x;
    if (SCAT && bid >= gnwg) {           // ---- scatter tail ----
        int i = (bid - gnwg) * 256 + threadIdx.x;
        if (i < E_EDGES) {
            int p = atomicAdd(&sc_cur1[sc_dst1[i]], 1);
            sc_srcs1[p] = sc_src1[i];
        } else {
            int j = i - E_EDGES;
            int p = atomicAdd(&sc_cur2[sc_dst2[j]], 1);
            sc_srcs2[p] = sc_src2[j];
        }
        return;
    }
    const int tid  = threadIdx.x;
    const int lane = tid & 63;
    const int wid  = tid >> 6;
    const int wr   = (wid >> 1) * (16 * MT);
    const int wc   = (wid & 1) * 64;

    const int nwg = gnwg;
    const int q = nwg >> 3, r = nwg & 7;
    const int xcd = bid & 7;
    const int wgid = (xcd < r ? xcd * (q + 1) : r * (q + 1) + (xcd - r) * q) + (bid >> 3);
    const int row0 = (wgid / ntx) * (32 * MT);
    const int col0 = (wgid % ntx) * 128;

    const int l4 = lane >> 2;
    const int lc = (lane & 3) * 8;

    const unsigned short* gA0;
    const unsigned short* gA1 = nullptr;
    if (MT == 2) {
        gA0 = A + (long)(row0 + 16 * wid + l4) * K + lc;
    } else {
        gA0 = A + (long)(row0 + 16 * (2 * wid) + l4) * K + lc;
        gA1 = A + (long)(row0 + 16 * (2 * wid + 1) + l4) * K + lc;
    }
    const unsigned short* gB0 = BT + (long)(col0 + 16 * (2 * wid) + l4) * K + lc;
    const unsigned short* gB1 = BT + (long)(col0 + 16 * (2 * wid + 1) + l4) * K + lc;

    f32x4 acc[MT][4] = {};

    for (int k0 = 0; k0 < K; k0 += 32 * KU) {
        __syncthreads();
#pragma unroll
        for (int u = 0; u < KU; ++u) {
            if (MT == 2) {
                gload16(gA0 + k0 + 32 * u, &a_s[u][16 * wid][0]);
            } else {
                gload16(gA0 + k0 + 32 * u, &a_s[u][32 * wid][0]);
                gload16(gA1 + k0 + 32 * u, &a_s[u][32 * wid + 16][0]);
            }
            gload16(gB0 + k0 + 32 * u, &b_s[u][32 * wid][0]);
            gload16(gB1 + k0 + 32 * u, &b_s[u][32 * wid + 16][0]);
        }
        __syncthreads();
#pragma unroll
        for (int u = 0; u < KU; ++u) {
            bf16x8 af[MT], bfr[4];
#pragma unroll
            for (int m = 0; m < MT; ++m)
                af[m] = *(const bf16x8*)&a_s[u][wr + m * 16 + (lane & 15)][8 * (lane >> 4)];
#pragma unroll
            for (int n = 0; n < 4; ++n)
                bfr[n] = *(const bf16x8*)&b_s[u][wc + n * 16 + (lane & 15)][8 * (lane >> 4)];
#pragma unroll
            for (int m = 0; m < MT; ++m)
#pragma unroll
                for (int n = 0; n < 4; ++n)
                    acc[m][n] = __builtin_amdgcn_mfma_f32_16x16x32_bf16(af[m], bfr[n], acc[m][n], 0, 0, 0);
        }
    }

#pragma unroll
    for (int m = 0; m < MT; ++m) {
        int row_t = wr + m * 16 + ((lane >> 4) << 2);
#pragma unroll
        for (int n = 0; n < 4; ++n) {
            int col = col0 + wc + n * 16 + (lane & 15);
#pragma unroll
            for (int r2 = 0; r2 < 4; ++r2) {
                int row = row0 + row_t + r2;
                float v = acc[m][n][r2];
                if (EPI >= 1) v += bias[col];
                if (EPI == 1) v = fmaxf(v, 0.f);
                if (EPI <= 1) {
                    ((unsigned short*)C)[(long)row * N + col] = f2bf(v);
                } else {
                    if (row < Mreal) ((float*)C)[(long)row * N + col] = v;
                }
            }
        }
    }

    if (NATT >= 1) {
        int hw = (col0 + wc) >> 6;
        float av0r[4], av1r[4];
#pragma unroll
        for (int n = 0; n < 4; ++n) {
            int c = col0 + wc + n * 16 + (lane & 15);
            av0r[n] = av0[c];
            if (NATT == 2) av1r[n] = av1[c];
        }
        float red0[MT * 4], red1[MT * 4];
#pragma unroll
        for (int m = 0; m < MT; ++m)
#pragma unroll
            for (int r2 = 0; r2 < 4; ++r2) {
                red0[m * 4 + r2] = acc[m][0][r2] * av0r[0] + acc[m][1][r2] * av0r[1]
                                 + acc[m][2][r2] * av0r[2] + acc[m][3][r2] * av0r[3];
                if (NATT == 2)
                    red1[m * 4 + r2] = acc[m][0][r2] * av1r[0] + acc[m][1][r2] * av1r[1]
                                     + acc[m][2][r2] * av1r[2] + acc[m][3][r2] * av1r[3];
            }
#pragma unroll
        for (int s = 1; s < 16; s <<= 1)
#pragma unroll
            for (int j = 0; j < MT * 4; ++j) {
                red0[j] += __shfl_xor(red0[j], s);
                if (NATT == 2) red1[j] += __shfl_xor(red1[j], s);
            }
        if ((lane & 15) == 0) {
#pragma unroll
            for (int m = 0; m < MT; ++m)
#pragma unroll
                for (int r2 = 0; r2 < 4; ++r2) {
                    int row = row0 + wr + m * 16 + ((lane >> 4) << 2) + r2;
                    eo0[row * 8 + hw] = red0[m * 4 + r2];
                    if (NATT == 2) eo1[row * 8 + hw] = red1[m * 4 + r2];
                }
        }
    }
}

// ---------------- scan (both graphs, one launch) ------------------------
__global__ void k_scan2(const int* __restrict__ cnt1, int* __restrict__ off1, int* __restrict__ cur1,
                        const int* __restrict__ cnt2, int* __restrict__ off2, int* __restrict__ cur2)
{
    const int* cnt = blockIdx.x ? cnt2 : cnt1;
    int* off = blockIdx.x ? off2 : off1;
    int* cur = blockIdx.x ? cur2 : cur1;
    __shared__ int partial[1024];
    int t = threadIdx.x;
    const int Nseg = NSECT;
    int chunk = (Nseg + 1023) / 1024;
    int b = t * chunk;
    int e_ = b + chunk; if (e_ > Nseg) e_ = Nseg; if (b > Nseg) b = Nseg;
    int s = 0;
    for (int i = b; i < e_; ++i) s += cnt[i];
    partial[t] = s;
    __syncthreads();
    for (int d = 1; d < 1024; d <<= 1) {
        int v = partial[t];
        int w = (t >= d) ? partial[t - d] : 0;
        __syncthreads();
        partial[t] = v + w;
        __syncthreads();
    }
    int run = (t == 0) ? 0 : partial[t - 1];
    for (int i = b; i < e_; ++i) { off[i] = run; cur[i] = run; run += cnt[i]; }
    if (t == 1023) off[Nseg] = partial[1023];
}

// -------- GAT aggregate core: max pass + fused denom/message pass -------
static __device__ __forceinline__ void agg_core(
    const unsigned short* __restrict__ fs, const float* __restrict__ el,
    const float* __restrict__ er, const float* __restrict__ bias,
    const int* __restrict__ off, const int* __restrict__ srcs,
    int n, int lane, float o[8])
{
    int h8 = lane & 7;
    int beg = off[n], end = off[n + 1];
    float er_h = er[n * 8 + h8];

    float mx = -3.0e38f;
    for (int p = beg + (lane >> 3); p < end; p += 8) {
        int s = srcs[p];
        float e = el[s * 8 + h8] + er_h;
        e = (e >= 0.f) ? e : 0.2f * e;
        mx = fmaxf(mx, e);
    }
    mx = fmaxf(mx, __shfl_xor(mx, 8));
    mx = fmaxf(mx, __shfl_xor(mx, 16));
    mx = fmaxf(mx, __shfl_xor(mx, 32));

    int hc = lane >> 3;                 // head owned by this lane's 8 dims
    float mx_c = __shfl(mx, hc);
    float er_c = er[n * 8 + hc];

    float a0=0,a1=0,a2=0,a3=0,a4=0,a5=0,a6=0,a7=0,sw=0;
    const unsigned short* fsl = fs + lane * 8;

#define ACC8(vv, ww)                                                   \
    a0 += (ww) * bf2f((unsigned short)((vv).x & 0xFFFF));              \
    a1 += (ww) * bf2f((unsigned short)((vv).x >> 16));                 \
    a2 += (ww) * bf2f((unsigned short)((vv).y & 0xFFFF));              \
    a3 += (ww) * bf2f((unsigned short)((vv).y >> 16));                 \
    a4 += (ww) * bf2f((unsigned short)((vv).z & 0xFFFF));              \
    a5 += (ww) * bf2f((unsigned short)((vv).z >> 16));                 \
    a6 += (ww) * bf2f((unsigned short)((vv).w & 0xFFFF));              \
    a7 += (ww) * bf2f((unsigned short)((vv).w >> 16));

    int p = beg;
    for (; p + 4 <= end; p += 4) {
        int s0 = srcs[p + 0], s1 = srcs[p + 1], s2 = srcs[p + 2], s3 = srcs[p + 3];
        float g0 = el[s0 * 8 + hc], g1 = el[s1 * 8 + hc];
        float g2 = el[s2 * 8 + hc], g3 = el[s3 * 8 + hc];
        uint4 v0 = *(const uint4*)(fsl + (long)s0 * 512);
        uint4 v1 = *(const uint4*)(fsl + (long)s1 * 512);
        uint4 v2 = *(const uint4*)(fsl + (long)s2 * 512);
        uint4 v3 = *(const uint4*)(fsl + (long)s3 * 512);
        float e0 = g0 + er_c; e0 = (e0 >= 0.f) ? e0 : 0.2f * e0; float w0 = __expf(e0 - mx_c);
        float e1 = g1 + er_c; e1 = (e1 >= 0.f) ? e1 : 0.2f * e1; float w1 = __expf(e1 - mx_c);
        float e2 = g2 + er_c; e2 = (e2 >= 0.f) ? e2 : 0.2f * e2; float w2 = __expf(e2 - mx_c);
        float e3 = g3 + er_c; e3 = (e3 >= 0.f) ? e3 : 0.2f * e3; float w3 = __expf(e3 - mx_c);
        sw += w0 + w1 + w2 + w3;
        ACC8(v0, w0); ACC8(v1, w1); ACC8(v2, w2); ACC8(v3, w3);
    }
    for (; p < end; ++p) {
        int s = srcs[p];
        float e = el[s * 8 + hc] + er_c;
        e = (e >= 0.f) ? e : 0.2f * e;
        float ww0 = __expf(e - mx_c);
        sw += ww0;
        uint4 v = *(const uint4*)(fsl + (long)s * 512);
        ACC8(v, ww0);
    }
#undef ACC8

    float inv = 1.f / fmaxf(sw, 1e-9f);
    const float* bp = bias + lane * 8;
    o[0] = a0*inv + bp[0]; o[1] = a1*inv + bp[1]; o[2] = a2*inv + bp[2]; o[3] = a3*inv + bp[3];
    o[4] = a4*inv + bp[4]; o[5] = a5*inv + bp[5]; o[6] = a6*inv + bp[6]; o[7] = a7*inv + bp[7];
#pragma unroll
    for (int j = 0; j < 8; ++j) o[j] = (o[j] > 0.f) ? o[j] : (__expf(o[j]) - 1.f);
}

// ---- both aggregates + fusion gate + residual, wave-per-(node,graph) ---
__global__ __launch_bounds__(256)
void k_agg_both(const unsigned short* __restrict__ fs1, const float* __restrict__ el1,
                const float* __restrict__ er1, const float* __restrict__ b1,
                const int* __restrict__ off1, const int* __restrict__ srcs1,
                const unsigned short* __restrict__ f2, const float* __restrict__ el2,
                const float* __restrict__ er2, const float* __restrict__ b2,
                const int* __restrict__ off2, const int* __restrict__ srcs2,
                const float* __restrict__ sect, const float* __restrict__ fw,
                const float* __restrict__ fb, unsigned short* __restrict__ hout)
{
    __shared__ float sh_o2[2][512];      // S2S result per local node, 4 KB
    int wid  = threadIdx.x >> 6;
    int lane = threadIdx.x & 63;
    int nloc = wid >> 1;
    int graph = wid & 1;
    int n = blockIdx.x * 2 + nloc;       // grid = NSECT_P/2, always in range
    bool real = (n < NSECT);

    float o1[8];
    if (real) {
        if (graph == 0) {
            agg_core(fs1, el1, er1, b1, off1, srcs1, n, lane, o1);   // s2S
        } else {
            float o2[8];
            agg_core(f2, el2, er2, b2, off2, srcs2, n, lane, o2);    // S2S
            *(float4*)&sh_o2[nloc][lane * 8]     = make_float4(o2[0], o2[1], o2[2], o2[3]);
            *(float4*)&sh_o2[nloc][lane * 8 + 4] = make_float4(o2[4], o2[5], o2[6], o2[7]);
        }
    }
    __syncthreads();
    if (graph != 0) return;
    long base = (long)n * TDIM + lane * 8;
    if (!real) {                          // pad rows of h: zero bf16
        *(uint4*)(hout + base) = make_uint4(0u, 0u, 0u, 0u);
        return;
    }
    float4 q0 = *(const float4*)&sh_o2[nloc][lane * 8];
    float4 q1 = *(const float4*)&sh_o2[nloc][lane * 8 + 4];
    float o2[8] = {q0.x, q0.y, q0.z, q0.w, q1.x, q1.y, q1.z, q1.w};

    float4 wa0 = *(const float4*)(fw + lane * 8);
    float4 wa1 = *(const float4*)(fw + lane * 8 + 4);
    float4 wb0 = *(const float4*)(fw + 512 + lane * 8);
    float4 wb1 = *(const float4*)(fw + 512 + lane * 8 + 4);
    float part = o1[0]*wa0.x + o1[1]*wa0.y + o1[2]*wa0.z + o1[3]*wa0.w
               + o1[4]*wa1.x + o1[5]*wa1.y + o1[6]*wa1.z + o1[7]*wa1.w
               + o2[0]*wb0.x + o2[1]*wb0.y + o2[2]*wb0.z + o2[3]*wb0.w
               + o2[4]*wb1.x + o2[5]*wb1.y + o2[6]*wb1.z + o2[7]*wb1.w;
#pragma unroll
    for (int s = 1; s < 64; s <<= 1) part += __shfl_xor(part, s);
    float z = 1.f / (1.f + __expf(-(part + fb[0])));
    float4 r0 = *(const float4*)(sect + base);
    float4 r1 = *(const float4*)(sect + base + 4);
    float hv[8];
    hv[0] = r0.x + z * o1[0] + (1.f - z) * o2[0];
    hv[1] = r0.y + z * o1[1] + (1.f - z) * o2[1];
    hv[2] = r0.z + z * o1[2] + (1.f - z) * o2[2];
    hv[3] = r0.w + z * o1[3] + (1.f - z) * o2[3];
    hv[4] = r1.x + z * o1[4] + (1.f - z) * o2[4];
    hv[5] = r1.y + z * o1[5] + (1.f - z) * o2[5];
    hv[6] = r1.z + z * o1[6] + (1.f - z) * o2[6];
    hv[7] = r1.w + z * o1[7] + (1.f - z) * o2[7];
    uint4 u;
    u.x = ((unsigned int)f2bf(hv[0])) | (((unsigned int)f2bf(hv[1])) << 16);
    u.y = ((unsigned int)f2bf(hv[2])) | (((unsigned int)f2bf(hv[3])) << 16);
    u.z = ((unsigned int)f2bf(hv[4])) | (((unsigned int)f2bf(hv[5])) << 16);
    u.w = ((unsigned int)f2bf(hv[6])) | (((unsigned int)f2bf(hv[7])) << 16);
    *(uint4*)(hout + base) = u;
}

// ------------------------------------------------------------------------
extern "C" void kernel_launch(void* const* d_in, const int* in_sizes, int n_in,
                              void* d_out, int out_size, void* d_ws, size_t ws_size,
                              hipStream_t stream)
{
    (void)in_sizes; (void)n_in; (void)out_size; (void)ws_size;
    const float* sent    = (const float*)d_in[0];
    const float* sect    = (const float*)d_in[1];
    const int*   s2S_src = (const int*)d_in[2];
    const int*   s2S_dst = (const int*)d_in[3];
    const int*   S2S_src = (const int*)d_in[4];
    const int*   S2S_dst = (const int*)d_in[5];
    const float* W1_src  = (const float*)d_in[6];
    const float* W1_dst  = (const float*)d_in[7];
    const float* al1     = (const float*)d_in[8];
    const float* ar1     = (const float*)d_in[9];
    const float* b1      = (const float*)d_in[10];
    const float* W2      = (const float*)d_in[11];
    const float* al2     = (const float*)d_in[12];
    const float* ar2     = (const float*)d_in[13];
    const float* b2      = (const float*)d_in[14];
    const float* fus_w   = (const float*)d_in[15];
    const float* fus_b   = (const float*)d_in[16];
    const float* ffn_w1  = (const float*)d_in[17];
    const float* ffn_b1  = (const float*)d_in[18];
    const float* ffn_w2  = (const float*)d_in[19];
    const float* ffn_b2  = (const float*)d_in[20];

    char* ws = (char*)d_ws;
    size_t curo = 0;
    auto alloc = [&](size_t sz) -> void* {
        void* p = ws + curo; curo += (sz + 255) & ~(size_t)255; return p;
    };

    unsigned short* sent_b = (unsigned short*)alloc((size_t)NSENT_P * SDIM * 2);
    unsigned short* sect_b = (unsigned short*)alloc((size_t)NSECT_P * TDIM * 2);
    unsigned short* w1t    = (unsigned short*)alloc((size_t)512 * 256 * 2);
    unsigned short* w2t    = (unsigned short*)alloc((size_t)512 * 512 * 2);
    unsigned short* fw1t   = (unsigned short*)alloc((size_t)2048 * 512 * 2);
    unsigned short* fw2t   = (unsigned short*)alloc((size_t)512 * 2048 * 2);
    float* Wr1 = (float*)alloc(512 * 8 * 4);
    float* el1 = (float*)alloc((size_t)NSENT_P * 8 * 4);
    float* er1 = (float*)alloc((size_t)NSECT_P * 8 * 4);
    float* el2 = (float*)alloc((size_t)NSECT_P * 8 * 4);
    float* er2 = (float*)alloc((size_t)NSECT_P * 8 * 4);
    unsigned short* fs1 = (unsigned short*)alloc((size_t)NSENT_P * 512 * 2);
    unsigned short* f2  = (unsigned short*)alloc((size_t)NSECT_P * 512 * 2);
    int* cnt1 = (int*)alloc((size_t)NSECT * 4);
    int* cnt2 = (int*)alloc((size_t)NSECT * 4);
    int* off1 = (int*)alloc((size_t)(NSECT + 1) * 4);
    int* off2 = (int*)alloc((size_t)(NSECT + 1) * 4);
    int* cur1 = (int*)alloc((size_t)NSECT * 4);
    int* cur2 = (int*)alloc((size_t)NSECT * 4);
    int* srcs1 = (int*)alloc((size_t)E_EDGES * 4);
    int* srcs2 = (int*)alloc((size_t)E_EDGES * 4);
    unsigned short* hb = (unsigned short*)alloc((size_t)NSECT_P * TDIM * 2);
    unsigned short* tb = fs1;   // alias: t[20096,2048] bf16 over fs1, fs1 dead by then

    // 1. prep: fold + transposes + cnt zeroing (one launch)
    k_prep<<<2606, 256, 0, stream>>>(W1_dst, ar1, Wr1, W1_src, w1t, W2, w2t,
                                     ffn_w1, fw1t, ffn_w2, fw2t, cnt1, cnt2);

    // 2. converts + er1 (Wr1 from step 1) + hist tail (one launch)
    k_convert_all<<<CONV_BLOCKS + HIST_BLOCKS, 256, 0, stream>>>(
        sent, sent_b, sect, sect_b, Wr1, er1, s2S_dst, cnt1, S2S_dst, cnt2);

    // 3. prefix scan (both graphs)
    k_scan2<<<2, 1024, 0, stream>>>(cnt1, off1, cur1, cnt2, off2, cur2);

    // 4. fs1 GEMM (+ fused scatter tail blocks) and f2 GEMM
    k_gemm<0, 1, 4, 2, 1><<<(NSENT_P / 128) * 4 + HIST_BLOCKS, 256, 0, stream>>>(
        sent_b, w1t, fs1, nullptr, 512, 256, 0, 4, (NSENT_P / 128) * 4,
        al1, el1, nullptr, nullptr,
        s2S_src, s2S_dst, cur1, srcs1, S2S_src, S2S_dst, cur2, srcs2);
    k_gemm<0, 2, 2, 2, 0><<<(NSECT_P / 64) * 4, 256, 0, stream>>>(
        sect_b, w2t, f2, nullptr, 512, 512, 0, 4, (NSECT_P / 64) * 4,
        al2, el2, ar2, er2,
        nullptr, nullptr, nullptr, nullptr, nullptr, nullptr, nullptr, nullptr);

    // 5. both aggregations + fusion gate + residual -> hb (one launch)
    k_agg_both<<<NSECT_P / 2, 256, 0, stream>>>(fs1, el1, er1, b1, off1, srcs1,
                                                f2, el2, er2, b2, off2, srcs2,
                                                sect, fus_w, fus_b, hb);

    // 6. FFN (KU=2 on both)
    k_gemm<1, 0, 4, 2, 0><<<(NSECT_P / 128) * (FFN / 128), 256, 0, stream>>>(
        hb, fw1t, tb, ffn_b1, FFN, 512, 0, FFN / 128, (NSECT_P / 128) * (FFN / 128),
        nullptr, nullptr, nullptr, nullptr,
        nullptr, nullptr, nullptr, nullptr, nullptr, nullptr, nullptr, nullptr);
    k_gemm<2, 0, 2, 2, 0><<<(NSECT_P / 64) * 4, 256, 0, stream>>>(
        tb, fw2t, d_out, ffn_b2, 512, FFN, NSECT, 4, (NSECT_P / 64) * 4,
        nullptr, nullptr, nullptr, nullptr,
        nullptr, nullptr, nullptr, nullptr, nullptr, nullptr, nullptr, nullptr);
}